// Round 2
// baseline (49.421 us; speedup 1.0000x reference)
//
#include <hip/hip_runtime.h>
#include <math.h>

// B=4096, O=8, E=64, I=4, V=3, P=perm(8,3)=336
// unary_feats  (B,8,64)   f32
// binary_feats (B,8,8,64) f32
// rule_unary   (4,3,64)   f32
// rule_binary  (4,3,3,64) f32
// out          (B,4)      f32  (col0=sel0+sel1, col1=sel2+sel3, col2=col3=0)
//
// Determinism structure: every __shared__ array has exactly ONE
// write-epoch -> __syncthreads -> read-epoch. No buffer reuse, no type-pun
// aliasing. Global memory: reads only (inputs), writes only (out, by tid 0).

#define NPERM 336
#define BM_STRIDE 66   // 36 rows; stride 66 so rule-group bases hit distinct banks

__global__ __launch_bounds__(256) void rule_learner_kernel(
    const float* __restrict__ uf,   // (B,8,64)
    const float* __restrict__ bf,   // (B,8,8,64)
    const float* __restrict__ ru,   // (4,3,64)
    const float* __restrict__ rb,   // (4,3,3,64)
    float* __restrict__ out)        // (B,4)
{
    const int b    = blockIdx.x;
    const int tid  = threadIdx.x;
    const int lane = tid & 63;
    const int wave = tid >> 6;

    __shared__ float4 rb4[36 * 16];          // 9216 B  binary rules
    __shared__ float  bm_s[36 * BM_STRIDE];  // 9504 B  binary match scores
    __shared__ float  ru_l[12 * 65];         // 3120 B  unary rules (pad 65)
    __shared__ float  uf_l[8 * 65];          // 2080 B  unary feats (pad 65)
    __shared__ float  u_l[96];               // unary dot results
    __shared__ float  wmin[16];              // per-wave per-rule mins

    // ---- write-epoch 1: stage rules + unary feats (coalesced) ----
    {
        const float4* rbg4 = (const float4*)rb;
        for (int q = tid; q < 576; q += 256) rb4[q] = rbg4[q];
        for (int q = tid; q < 768; q += 256) ru_l[(q >> 6) * 65 + (q & 63)] = ru[q];
        const float* ufg = uf + (size_t)b * 512;
        for (int q = tid; q < 512; q += 256) uf_l[(q >> 6) * 65 + (q & 63)] = ufg[q];
    }

    // ---- each lane pulls its binary-feat row (j,k)=lane straight from global.
    // Wave reads a contiguous 16KB region over its 16 instrs; L1 absorbs the
    // per-instruction stride-256 scatter; waves 1-3 hit L1.
    float feat[64];
    {
        const float4* bfg4 = (const float4*)(bf + (size_t)b * 4096) + lane * 16;
        #pragma unroll
        for (int q = 0; q < 16; ++q) {
            float4 v = bfg4[q];
            feat[4 * q + 0] = v.x; feat[4 * q + 1] = v.y;
            feat[4 * q + 2] = v.z; feat[4 * q + 3] = v.w;
        }
    }
    __syncthreads();   // rb4 / ru_l / uf_l now readable

    // ---- write-epoch 2: binary scores (wave w owns rules w*9 .. w*9+8),
    //      plus unary dots on threads 0..95 ----
    {
        float acc[9];
        #pragma unroll
        for (int r = 0; r < 9; ++r) acc[r] = 0.f;
        const int rbase = wave * 9;
        #pragma unroll
        for (int e4 = 0; e4 < 16; ++e4) {
            const float f0 = feat[4 * e4 + 0], f1 = feat[4 * e4 + 1];
            const float f2 = feat[4 * e4 + 2], f3 = feat[4 * e4 + 3];
            #pragma unroll
            for (int r = 0; r < 9; ++r) {
                float4 rv = rb4[(rbase + r) * 16 + e4];   // uniform addr -> broadcast
                acc[r] = fmaf(f0, rv.x, acc[r]);
                acc[r] = fmaf(f1, rv.y, acc[r]);
                acc[r] = fmaf(f2, rv.z, acc[r]);
                acc[r] = fmaf(f3, rv.w, acc[r]);
            }
        }
        #pragma unroll
        for (int r = 0; r < 9; ++r) bm_s[(rbase + r) * BM_STRIDE + lane] = acc[r];
    }
    if (tid < 96) {   // t = i*24 + k*8 + l
        const int i = tid / 24;
        const int k = (tid >> 3) % 3;
        const int l = tid & 7;
        const float* rp = ru_l + (i * 3 + k) * 65;
        const float* up = uf_l + l * 65;
        float s = 0.f;
        #pragma unroll
        for (int e = 0; e < 64; ++e) s = fmaf(up[e], rp[e], s);
        u_l[tid] = s;
    }
    __syncthreads();   // bm_s / u_l now readable

    // ---- gather over permutations; thread owns rule i = tid&3,
    //      perm slots p = (tid>>2) + pk*64 (each p in 0..335 covered once) ----
    const int i = tid & 3;
    const float* bmi = bm_s + i * (9 * BM_STRIDE);
    const float* ui  = u_l + i * 24;
    float mn = INFINITY;
    #pragma unroll
    for (int pk = 0; pk < 6; ++pk) {
        int p = (tid >> 2) + pk * 64;
        if (p < NPERM) {
            int a   = p / 42;
            int rem = p - a * 42;
            int b1  = rem / 6;
            int c1  = rem - b1 * 6;
            int bb  = b1 + (b1 >= a);
            int lo  = min(a, bb), hi = max(a, bb);
            int cc  = c1 + (c1 >= lo);
            cc += (cc >= hi);
            float s = ui[a] + ui[8 + bb] + ui[16 + cc];
            s += bmi[0 * BM_STRIDE + a  * 8 + a ];
            s += bmi[1 * BM_STRIDE + a  * 8 + bb];
            s += bmi[2 * BM_STRIDE + a  * 8 + cc];
            s += bmi[3 * BM_STRIDE + bb * 8 + a ];
            s += bmi[4 * BM_STRIDE + bb * 8 + bb];
            s += bmi[5 * BM_STRIDE + bb * 8 + cc];
            s += bmi[6 * BM_STRIDE + cc * 8 + a ];
            s += bmi[7 * BM_STRIDE + cc * 8 + bb];
            s += bmi[8 * BM_STRIDE + cc * 8 + cc];
            mn = fminf(mn, s);
        }
    }

    // min over the 16 lanes sharing (lane&3)
    mn = fminf(mn, __shfl_xor(mn, 4));
    mn = fminf(mn, __shfl_xor(mn, 8));
    mn = fminf(mn, __shfl_xor(mn, 16));
    mn = fminf(mn, __shfl_xor(mn, 32));

    // ---- write-epoch 3: per-wave mins ----
    if (lane < 4) wmin[wave * 4 + lane] = mn;
    __syncthreads();

    if (tid == 0) {
        float m0 = fminf(fminf(wmin[0], wmin[4]), fminf(wmin[8],  wmin[12]));
        float m1 = fminf(fminf(wmin[1], wmin[5]), fminf(wmin[9],  wmin[13]));
        float m2 = fminf(fminf(wmin[2], wmin[6]), fminf(wmin[10], wmin[14]));
        float m3 = fminf(fminf(wmin[3], wmin[7]), fminf(wmin[11], wmin[15]));
        float mx = fmaxf(fmaxf(m0, m1), fmaxf(m2, m3));
        float e0 = expf(m0 - mx), e1 = expf(m1 - mx);
        float e2 = expf(m2 - mx), e3 = expf(m3 - mx);
        float inv = 1.f / (e0 + e1 + e2 + e3);
        *(float4*)(out + (size_t)b * 4) =
            make_float4((e0 + e1) * inv, (e2 + e3) * inv, 0.f, 0.f);
    }
}

extern "C" void kernel_launch(void* const* d_in, const int* in_sizes, int n_in,
                              void* d_out, int out_size, void* d_ws, size_t ws_size,
                              hipStream_t stream) {
    const float* uf = (const float*)d_in[0];   // (4096,8,64)
    const float* bf = (const float*)d_in[1];   // (4096,8,8,64)
    const float* ru = (const float*)d_in[2];   // (4,3,64)
    const float* rb = (const float*)d_in[3];   // (4,3,3,64)
    float* out = (float*)d_out;                // (4096,4)

    const int B = in_sizes[0] / (8 * 64);      // 4096
    rule_learner_kernel<<<B, 256, 0, stream>>>(uf, bf, ru, rb, out);
}

// Round 3
// 47.872 us; speedup vs baseline: 1.0324x; 1.0324x over previous
//
#include <hip/hip_runtime.h>
#include <math.h>

// B=4096, O=8, E=64, I=4, V=3, P=perm(8,3)=336
// unary_feats  (B,8,64)   f32
// binary_feats (B,8,8,64) f32
// rule_unary   (4,3,64)   f32
// rule_binary  (4,3,3,64) f32
// out          (B,4)      f32  (col0=sel0+sel1, col1=sel2+sel3, col2=col3=0)
//
// v3: rule tensors are wave-uniform (wave w handles rule-set i=w), so all rule
// element reads go through the SCALAR path (s_load via readfirstlane-proven
// uniform addresses) and feed v_fmac as the 1-SGPR operand. Zero LDS traffic
// for the match GEMMs; LDS only holds bm scores + unary results for the
// permutation gather. Every __shared__ array: one write-epoch -> barrier ->
// read-epoch.

#define NPERM 336
#define BM_STRIDE 66   // 36 rows; 66 spreads the 4 rule-group bases across banks

__global__ __launch_bounds__(256) void rule_learner_kernel(
    const float* __restrict__ uf,   // (B,8,64)
    const float* __restrict__ bf,   // (B,8,8,64)
    const float* __restrict__ ru,   // (4,3,64)
    const float* __restrict__ rb,   // (4,3,3,64)
    float* __restrict__ out)        // (B,4)
{
    const int b    = blockIdx.x;
    const int tid  = threadIdx.x;
    const int lane = tid & 63;
    const int iw   = __builtin_amdgcn_readfirstlane(tid >> 6); // wave-uniform rule set

    __shared__ float bm_s[36 * BM_STRIDE];  // binary match scores
    __shared__ float u_l[96];               // unary match scores (pair*8 + l)
    __shared__ float wmin[16];              // per-wave per-rule mins

    // ---- binary match: wave iw computes rules iw*9..iw*9+8 over all 64 (j,k).
    // Rule elems: scalar loads (uniform). Features: per-lane global row (L1-hot
    // for waves 1-3 since all waves read the same 16KB block region).
    {
        const float* rbw = rb + iw * 576;   // 9 rules x 64 elems, wave-uniform base
        const float4* fg = (const float4*)(bf + (size_t)b * 4096) + lane * 16;
        float acc[9];
        #pragma unroll
        for (int r = 0; r < 9; ++r) acc[r] = 0.f;
        #pragma unroll
        for (int q = 0; q < 16; ++q) {
            const float4 v = fg[q];
            #pragma unroll
            for (int r = 0; r < 9; ++r) acc[r] = fmaf(rbw[r * 64 + 4 * q + 0], v.x, acc[r]);
            #pragma unroll
            for (int r = 0; r < 9; ++r) acc[r] = fmaf(rbw[r * 64 + 4 * q + 1], v.y, acc[r]);
            #pragma unroll
            for (int r = 0; r < 9; ++r) acc[r] = fmaf(rbw[r * 64 + 4 * q + 2], v.z, acc[r]);
            #pragma unroll
            for (int r = 0; r < 9; ++r) acc[r] = fmaf(rbw[r * 64 + 4 * q + 3], v.w, acc[r]);
        }
        #pragma unroll
        for (int r = 0; r < 9; ++r) bm_s[(iw * 9 + r) * BM_STRIDE + lane] = acc[r];
    }

    // ---- unary match: lanes 0..7 of wave iw compute dot(uf[l], ru[iw][k]) for
    // k=0..2, l=lane. Rule elems scalar, features per-lane global (tiny, L1).
    if (lane < 8) {
        const float* ruw = ru + iw * 192;   // 3 rules x 64, wave-uniform base
        const float4* ug = (const float4*)(uf + (size_t)b * 512) + lane * 16;
        float au0 = 0.f, au1 = 0.f, au2 = 0.f;
        #pragma unroll
        for (int q = 0; q < 16; ++q) {
            const float4 v = ug[q];
            au0 = fmaf(ruw[0 * 64 + 4 * q + 0], v.x, au0);
            au1 = fmaf(ruw[1 * 64 + 4 * q + 0], v.x, au1);
            au2 = fmaf(ruw[2 * 64 + 4 * q + 0], v.x, au2);
            au0 = fmaf(ruw[0 * 64 + 4 * q + 1], v.y, au0);
            au1 = fmaf(ruw[1 * 64 + 4 * q + 1], v.y, au1);
            au2 = fmaf(ruw[2 * 64 + 4 * q + 1], v.y, au2);
            au0 = fmaf(ruw[0 * 64 + 4 * q + 2], v.z, au0);
            au1 = fmaf(ruw[1 * 64 + 4 * q + 2], v.z, au1);
            au2 = fmaf(ruw[2 * 64 + 4 * q + 2], v.z, au2);
            au0 = fmaf(ruw[0 * 64 + 4 * q + 3], v.w, au0);
            au1 = fmaf(ruw[1 * 64 + 4 * q + 3], v.w, au1);
            au2 = fmaf(ruw[2 * 64 + 4 * q + 3], v.w, au2);
        }
        u_l[(iw * 3 + 0) * 8 + lane] = au0;
        u_l[(iw * 3 + 1) * 8 + lane] = au1;
        u_l[(iw * 3 + 2) * 8 + lane] = au2;
    }
    __syncthreads();   // bm_s / u_l now readable

    // ---- gather over permutations; thread owns rule i = tid&3,
    //      perm slots p = (tid>>2) + pk*64 ----
    const int i = tid & 3;
    const float* bmi = bm_s + i * (9 * BM_STRIDE);
    const float* ui  = u_l + i * 24;
    float mn = INFINITY;
    #pragma unroll
    for (int pk = 0; pk < 6; ++pk) {
        int p = (tid >> 2) + pk * 64;
        if (p < NPERM) {
            int a   = p / 42;
            int rem = p - a * 42;
            int b1  = rem / 6;
            int c1  = rem - b1 * 6;
            int bb  = b1 + (b1 >= a);
            int lo  = min(a, bb), hi = max(a, bb);
            int cc  = c1 + (c1 >= lo);
            cc += (cc >= hi);
            float s = ui[a] + ui[8 + bb] + ui[16 + cc];
            s += bmi[0 * BM_STRIDE + a  * 8 + a ];
            s += bmi[1 * BM_STRIDE + a  * 8 + bb];
            s += bmi[2 * BM_STRIDE + a  * 8 + cc];
            s += bmi[3 * BM_STRIDE + bb * 8 + a ];
            s += bmi[4 * BM_STRIDE + bb * 8 + bb];
            s += bmi[5 * BM_STRIDE + bb * 8 + cc];
            s += bmi[6 * BM_STRIDE + cc * 8 + a ];
            s += bmi[7 * BM_STRIDE + cc * 8 + bb];
            s += bmi[8 * BM_STRIDE + cc * 8 + cc];
            mn = fminf(mn, s);
        }
    }

    // min over the 16 lanes sharing (lane&3)
    mn = fminf(mn, __shfl_xor(mn, 4));
    mn = fminf(mn, __shfl_xor(mn, 8));
    mn = fminf(mn, __shfl_xor(mn, 16));
    mn = fminf(mn, __shfl_xor(mn, 32));

    if (lane < 4) wmin[iw * 4 + lane] = mn;
    __syncthreads();

    if (tid == 0) {
        float m0 = fminf(fminf(wmin[0], wmin[4]), fminf(wmin[8],  wmin[12]));
        float m1 = fminf(fminf(wmin[1], wmin[5]), fminf(wmin[9],  wmin[13]));
        float m2 = fminf(fminf(wmin[2], wmin[6]), fminf(wmin[10], wmin[14]));
        float m3 = fminf(fminf(wmin[3], wmin[7]), fminf(wmin[11], wmin[15]));
        float mx = fmaxf(fmaxf(m0, m1), fmaxf(m2, m3));
        float e0 = expf(m0 - mx), e1 = expf(m1 - mx);
        float e2 = expf(m2 - mx), e3 = expf(m3 - mx);
        float inv = 1.f / (e0 + e1 + e2 + e3);
        *(float4*)(out + (size_t)b * 4) =
            make_float4((e0 + e1) * inv, (e2 + e3) * inv, 0.f, 0.f);
    }
}

extern "C" void kernel_launch(void* const* d_in, const int* in_sizes, int n_in,
                              void* d_out, int out_size, void* d_ws, size_t ws_size,
                              hipStream_t stream) {
    const float* uf = (const float*)d_in[0];   // (4096,8,64)
    const float* bf = (const float*)d_in[1];   // (4096,8,8,64)
    const float* ru = (const float*)d_in[2];   // (4,3,64)
    const float* rb = (const float*)d_in[3];   // (4,3,3,64)
    float* out = (float*)d_out;                // (4096,4)

    const int B = in_sizes[0] / (8 * 64);      // 4096
    rule_learner_kernel<<<B, 256, 0, stream>>>(uf, bf, ru, rb, out);
}

// Round 4
// 35.206 us; speedup vs baseline: 1.4038x; 1.3598x over previous
//
#include <hip/hip_runtime.h>
#include <math.h>

// B=4096, O=8, E=64, I=4, V=3, P=perm(8,3)=336
// unary_feats  (B,8,64)   f32
// binary_feats (B,8,8,64) f32
// rule_unary   (4,3,64)   f32
// rule_binary  (4,3,3,64) f32  (= [36][64] rules)
// out          (B,4)      f32  (col0=sel0+sel1, col1=sel2+sel3, col2=col3=0)
//
// v4: binary match = per-block 64x36x64 GEMM -> v_mfma_f32_16x16x32_bf16.
// A/B fragments load straight from global fp32 and convert in-reg (rules are
// L1/L2-hot). Gather compressed into 3 pair-tables (Q01/Q02/Q12) so each
// (rule, a, b) thread does 1 b32 + 4 b128 LDS reads and an 8-wide cc sweep.
// Every __shared__ array: one write-epoch -> barrier -> read-epoch.

typedef __attribute__((ext_vector_type(8))) __bf16 bf16x8;
typedef __attribute__((ext_vector_type(4))) float  f32x4;

#define BM_STRIDE 66   // bm rows; odd-ish stride spreads banks
#define QROW 12        // Q-table row stride (floats); 48B keeps float4 alignment

__device__ inline bf16x8 load_bf16x8(const float* __restrict__ p) {
    const float4 v0 = *(const float4*)p;
    const float4 v1 = *(const float4*)(p + 4);
    bf16x8 r;
    r[0] = (__bf16)v0.x; r[1] = (__bf16)v0.y; r[2] = (__bf16)v0.z; r[3] = (__bf16)v0.w;
    r[4] = (__bf16)v1.x; r[5] = (__bf16)v1.y; r[6] = (__bf16)v1.z; r[7] = (__bf16)v1.w;
    return r;
}

__device__ inline bf16x8 zero_bf16x8() {
    bf16x8 r;
    #pragma unroll
    for (int t = 0; t < 8; ++t) r[t] = (__bf16)0.0f;
    return r;
}

__global__ __launch_bounds__(256) void rule_learner_kernel(
    const float* __restrict__ uf,   // (B,8,64)
    const float* __restrict__ bf,   // (B,8,8,64)
    const float* __restrict__ ru,   // (4,3,64) = [12][64]
    const float* __restrict__ rb,   // (4,3,3,64) = [36][64]
    float* __restrict__ out)        // (B,4)
{
    const int b    = blockIdx.x;
    const int tid  = threadIdx.x;
    const int lane = tid & 63;
    const int w    = tid >> 6;       // wave id = position strip (binary GEMM)

    const int row16 = lane & 15;     // A row within 16-tile / B col within 16-tile
    const int kg    = lane >> 4;     // k group (0..3)
    const int kb    = kg * 8;        // k base within a 32-wide K instruction

    __shared__ float bm_s[36 * BM_STRIDE];  // binary match [rule][pos]
    __shared__ float um_s[12 * 8];          // unary match  [i*3+n][obj]
    __shared__ float q01_s[32 * QROW];      // row (x*4+i), col y
    __shared__ float q02_s[32 * QROW];
    __shared__ float q12_s[32 * QROW];
    __shared__ float wmin[16];

    // ================= Phase 1: MFMA matches =================
    // Binary: wave w computes C[pos=w*16..w*16+15][rule 0..47(pad)] with K=64.
    {
        const float* Abase = bf + (size_t)b * 4096 + (size_t)(w * 16 + row16) * 64 + kb;
        const bf16x8 a0 = load_bf16x8(Abase);        // k in [0,32)
        const bf16x8 a1 = load_bf16x8(Abase + 32);   // k in [32,64)
        #pragma unroll
        for (int nt = 0; nt < 3; ++nt) {
            const int rule = nt * 16 + row16;
            bf16x8 b0, b1;
            if (rule < 36) {
                const float* Bb = rb + rule * 64 + kb;
                b0 = load_bf16x8(Bb);
                b1 = load_bf16x8(Bb + 32);
            } else {
                b0 = zero_bf16x8();
                b1 = zero_bf16x8();
            }
            f32x4 acc = {0.f, 0.f, 0.f, 0.f};
            acc = __builtin_amdgcn_mfma_f32_16x16x32_bf16(a0, b0, acc, 0, 0, 0);
            acc = __builtin_amdgcn_mfma_f32_16x16x32_bf16(a1, b1, acc, 0, 0, 0);
            // C layout (m89): col = lane&15 (rule), row = (lane>>4)*4 + reg (pos)
            if (rule < 36) {
                const int pos = w * 16 + kg * 4;
                #pragma unroll
                for (int r = 0; r < 4; ++r)
                    bm_s[rule * BM_STRIDE + pos + r] = acc[r];
            }
        }
    }
    // Unary (wave 3): C[obj 0..7][ruleu 0..11] with K=64, padded to 16x16.
    if (w == 3) {
        bf16x8 a0, a1, b0, b1;
        if (row16 < 8) {
            const float* Ab = uf + (size_t)b * 512 + row16 * 64 + kb;
            a0 = load_bf16x8(Ab); a1 = load_bf16x8(Ab + 32);
        } else { a0 = zero_bf16x8(); a1 = zero_bf16x8(); }
        if (row16 < 12) {
            const float* Bb = ru + row16 * 64 + kb;
            b0 = load_bf16x8(Bb); b1 = load_bf16x8(Bb + 32);
        } else { b0 = zero_bf16x8(); b1 = zero_bf16x8(); }
        f32x4 acc = {0.f, 0.f, 0.f, 0.f};
        acc = __builtin_amdgcn_mfma_f32_16x16x32_bf16(a0, b0, acc, 0, 0, 0);
        acc = __builtin_amdgcn_mfma_f32_16x16x32_bf16(a1, b1, acc, 0, 0, 0);
        if (row16 < 12 && kg < 2) {     // rows (objects) 0..7 live in kg 0,1
            #pragma unroll
            for (int r = 0; r < 4; ++r)
                um_s[row16 * 8 + kg * 4 + r] = acc[r];
        }
    }
    __syncthreads();   // bm_s / um_s readable

    // ================= Phase 2: build pair tables =================
    // score(i; a,b,c) = Q01[i][a][b] + Q02[i][a][c] + Q12[i][b][c]
    // Q01 = um0[x]+um1[y]+bm00[x,x]+bm11[y,y]+bm01[x,y]+bm10[y,x]
    // Q02 = um2[y]+bm22[y,y]+bm02[x,y]+bm20[y,x]
    // Q12 = bm12[x,y]+bm21[y,x]
    {
        const int i = tid >> 6;          // rule set
        const int x = (tid >> 3) & 7;
        const int y = tid & 7;
        const float* bmi = bm_s + i * 9 * BM_STRIDE;
        const float q01 = um_s[(i * 3 + 0) * 8 + x] + um_s[(i * 3 + 1) * 8 + y]
                        + bmi[0 * BM_STRIDE + x * 9] + bmi[4 * BM_STRIDE + y * 9]
                        + bmi[1 * BM_STRIDE + x * 8 + y] + bmi[3 * BM_STRIDE + y * 8 + x];
        const float q02 = um_s[(i * 3 + 2) * 8 + y] + bmi[8 * BM_STRIDE + y * 9]
                        + bmi[2 * BM_STRIDE + x * 8 + y] + bmi[6 * BM_STRIDE + y * 8 + x];
        const float q12 = bmi[5 * BM_STRIDE + x * 8 + y] + bmi[7 * BM_STRIDE + y * 8 + x];
        const int ro = (x * 4 + i) * QROW + y;
        q01_s[ro] = q01; q02_s[ro] = q02; q12_s[ro] = q12;
    }
    __syncthreads();   // q tables readable

    // ================= Phase 3: permutation sweep =================
    // thread owns (i = tid&3, ordered pair pr = tid>>2 < 56 -> (a,bb)), sweeps cc.
    float mn = INFINITY;
    {
        const int i  = tid & 3;
        const int pr = tid >> 2;
        if (pr < 56) {
            const int a  = pr / 7;
            const int o  = pr - a * 7;
            const int bb = o + (o >= a);
            const float base = q01_s[(a * 4 + i) * QROW + bb];
            const float4 r2a = *(const float4*)&q02_s[(a  * 4 + i) * QROW];
            const float4 r2b = *(const float4*)&q02_s[(a  * 4 + i) * QROW + 4];
            const float4 r1a = *(const float4*)&q12_s[(bb * 4 + i) * QROW];
            const float4 r1b = *(const float4*)&q12_s[(bb * 4 + i) * QROW + 4];
            float v[8];
            v[0] = r2a.x + r1a.x; v[1] = r2a.y + r1a.y;
            v[2] = r2a.z + r1a.z; v[3] = r2a.w + r1a.w;
            v[4] = r2b.x + r1b.x; v[5] = r2b.y + r1b.y;
            v[6] = r2b.z + r1b.z; v[7] = r2b.w + r1b.w;
            #pragma unroll
            for (int cc = 0; cc < 8; ++cc) {
                const float s = (cc == a || cc == bb) ? INFINITY : (base + v[cc]);
                mn = fminf(mn, s);
            }
        }
    }

    // min over the 16 lanes sharing (lane&3)
    mn = fminf(mn, __shfl_xor(mn, 4));
    mn = fminf(mn, __shfl_xor(mn, 8));
    mn = fminf(mn, __shfl_xor(mn, 16));
    mn = fminf(mn, __shfl_xor(mn, 32));

    if (lane < 4) wmin[w * 4 + lane] = mn;
    __syncthreads();

    if (tid == 0) {
        float m0 = fminf(fminf(wmin[0], wmin[4]), fminf(wmin[8],  wmin[12]));
        float m1 = fminf(fminf(wmin[1], wmin[5]), fminf(wmin[9],  wmin[13]));
        float m2 = fminf(fminf(wmin[2], wmin[6]), fminf(wmin[10], wmin[14]));
        float m3 = fminf(fminf(wmin[3], wmin[7]), fminf(wmin[11], wmin[15]));
        float mx = fmaxf(fmaxf(m0, m1), fmaxf(m2, m3));
        float e0 = expf(m0 - mx), e1 = expf(m1 - mx);
        float e2 = expf(m2 - mx), e3 = expf(m3 - mx);
        float inv = 1.f / (e0 + e1 + e2 + e3);
        *(float4*)(out + (size_t)b * 4) =
            make_float4((e0 + e1) * inv, (e2 + e3) * inv, 0.f, 0.f);
    }
}

extern "C" void kernel_launch(void* const* d_in, const int* in_sizes, int n_in,
                              void* d_out, int out_size, void* d_ws, size_t ws_size,
                              hipStream_t stream) {
    const float* uf = (const float*)d_in[0];   // (4096,8,64)
    const float* bf = (const float*)d_in[1];   // (4096,8,8,64)
    const float* ru = (const float*)d_in[2];   // (4,3,64)
    const float* rb = (const float*)d_in[3];   // (4,3,3,64)
    float* out = (float*)d_out;                // (4096,4)

    const int B = in_sizes[0] / (8 * 64);      // 4096
    rule_learner_kernel<<<B, 256, 0, stream>>>(uf, bf, ru, rb, out);
}

// Round 5
// 30.410 us; speedup vs baseline: 1.6252x; 1.1577x over previous
//
#include <hip/hip_runtime.h>
#include <math.h>

// B=4096, O=8, E=64, I=4, V=3, P=perm(8,3)=336
// unary_feats  (B,8,64)   f32
// binary_feats (B,8,8,64) f32
// rule_unary   (4,3,64)   f32  = [12][64]
// rule_binary  (4,3,3,64) f32  = [36][64]
// out          (B,4)      f32  (col0=sel0+sel1, col1=sel2+sel3, col2=col3=0)
//
// v5: rules pre-packed ONCE (prep kernel) into d_ws as bf16 MFMA B-fragments
// (zero-padded to 16-wide tiles) -> main kernel B-load = 1 dwordx4, no cvt,
// no branches. Binary match via v_mfma_f32_16x16x32_bf16. bm stored
// TRANSPOSED [pos][col] with column-permuted rule slots + unary scores fused
// into spare columns, so phase2 = 3x ds_read_b128 + 1x ds_read_b64.
// Slot map (per rule-set i, col = i*16+slot):
//   0..2 : r1(01), r2(02), r5(12)   read at row (x*8+y)
//   4..6 : r3(10), r6(20), r7(21)   read at row (y*8+x)
//   8..11: r4(11), r8(22), um1, um2 read at row (y*8+y)
//   12,13: r0(00), um0              read at row (x*8+x)

typedef __attribute__((ext_vector_type(8))) __bf16 bf16x8;
typedef __attribute__((ext_vector_type(4))) float  f32x4;

#define BMT_STRIDE 68   // floats; (row*68)/4 mod 8 == row mod 8 -> clean b128
#define QROW 20         // q-table row stride (floats), 16B-aligned rows

__device__ inline bf16x8 load_bf16x8(const float* __restrict__ p) {
    const float4 v0 = *(const float4*)p;
    const float4 v1 = *(const float4*)(p + 4);
    bf16x8 r;
    r[0] = (__bf16)v0.x; r[1] = (__bf16)v0.y; r[2] = (__bf16)v0.z; r[3] = (__bf16)v0.w;
    r[4] = (__bf16)v1.x; r[5] = (__bf16)v1.y; r[6] = (__bf16)v1.z; r[7] = (__bf16)v1.w;
    return r;
}

__device__ inline bf16x8 zero_bf16x8() {
    bf16x8 r;
    #pragma unroll
    for (int t = 0; t < 8; ++t) r[t] = (__bf16)0.0f;
    return r;
}

// ---- prep: pack rules as bf16 MFMA B-fragments into ws ----
// layout (bf16): [nt(3)][h(2)][lane(64)][e(8)]  then unary [h(2)][lane(64)][e(8)]
__global__ __launch_bounds__(256) void rule_prep_kernel(
    const float* __restrict__ ru, const float* __restrict__ rb,
    __bf16* __restrict__ wsb)
{
    for (int idx = threadIdx.x; idx < 4096; idx += 256) {
        float val;
        if (idx < 3072) {
            const int nt   = idx >> 10;
            const int rem  = idx & 1023;
            const int h    = rem >> 9;
            const int lane = (rem >> 3) & 63;
            const int e    = rem & 7;
            const int rule = nt * 16 + (lane & 15);
            const int k    = h * 32 + (lane >> 4) * 8 + e;
            val = (rule < 36) ? rb[rule * 64 + k] : 0.f;
        } else {
            const int u    = idx - 3072;
            const int h    = u >> 9;
            const int lane = (u >> 3) & 63;
            const int e    = u & 7;
            const int ru16 = lane & 15;
            const int k    = h * 32 + (lane >> 4) * 8 + e;
            val = (ru16 < 12) ? ru[ru16 * 64 + k] : 0.f;
        }
        wsb[idx] = (__bf16)val;
    }
}

__global__ __launch_bounds__(256) void rule_learner_kernel(
    const float* __restrict__ uf,    // (B,8,64)
    const float* __restrict__ bfe,   // (B,8,8,64)
    const bf16x8* __restrict__ wsb,  // packed rule fragments
    float* __restrict__ out)         // (B,4)
{
    const int b     = blockIdx.x;
    const int tid   = threadIdx.x;
    const int lane  = tid & 63;
    const int w     = tid >> 6;      // wave id = position strip
    const int row16 = lane & 15;
    const int kg    = lane >> 4;
    const int kb    = kg * 8;

    __shared__ float bm_t[64 * BMT_STRIDE];  // 17408 B
    __shared__ float q01_s[32 * QROW];       // 2560 B
    __shared__ float q02_s[32 * QROW];
    __shared__ float q12_s[32 * QROW];
    __shared__ float wmin[16];

    // ---- Phase 1: MFMA matches ----
    {
        const float* Abase = bfe + (size_t)b * 4096 + (size_t)(w * 16 + row16) * 64 + kb;
        const bf16x8 a0 = load_bf16x8(Abase);
        const bf16x8 a1 = load_bf16x8(Abase + 32);
        #pragma unroll
        for (int nt = 0; nt < 3; ++nt) {
            const bf16x8 b0 = wsb[(nt * 2 + 0) * 64 + lane];
            const bf16x8 b1 = wsb[(nt * 2 + 1) * 64 + lane];
            f32x4 acc = {0.f, 0.f, 0.f, 0.f};
            acc = __builtin_amdgcn_mfma_f32_16x16x32_bf16(a0, b0, acc, 0, 0, 0);
            acc = __builtin_amdgcn_mfma_f32_16x16x32_bf16(a1, b1, acc, 0, 0, 0);
            // C layout: col(lane&15)=rule within tile, row=(lane>>4)*4+reg = pos
            const int rule = nt * 16 + row16;
            if (rule < 36) {
                const int i = rule / 9;
                const int r = rule - i * 9;
                const int n = r / 3, m = r - n * 3;
                int slot;
                if (n < m)      slot = n + m - 1;         // 01,02,12 -> 0,1,2
                else if (n > m) slot = 3 + n + m;         // 10,20,21 -> 4,5,6
                else            slot = (n == 0) ? 12 : 7 + n;  // 00,11,22 -> 12,8,9
                const int col  = i * 16 + slot;
                const int pos0 = w * 16 + kg * 4;
                #pragma unroll
                for (int t = 0; t < 4; ++t)
                    bm_t[(pos0 + t) * BMT_STRIDE + col] = acc[t];
            }
        }
    }
    // unary match (wave 3): C[obj][ruleu], ruleu = i*3+n
    if (w == 3) {
        bf16x8 a0, a1;
        if (row16 < 8) {
            const float* Ab = uf + (size_t)b * 512 + row16 * 64 + kb;
            a0 = load_bf16x8(Ab); a1 = load_bf16x8(Ab + 32);
        } else { a0 = zero_bf16x8(); a1 = zero_bf16x8(); }
        const bf16x8 b0 = wsb[384 + lane];        // unary frags start at bf16 idx 3072
        const bf16x8 b1 = wsb[384 + 64 + lane];
        f32x4 acc = {0.f, 0.f, 0.f, 0.f};
        acc = __builtin_amdgcn_mfma_f32_16x16x32_bf16(a0, b0, acc, 0, 0, 0);
        acc = __builtin_amdgcn_mfma_f32_16x16x32_bf16(a1, b1, acc, 0, 0, 0);
        if (row16 < 12 && kg < 2) {               // objs 0..7 live in kg 0,1
            const int iu = row16 / 3;
            const int nn = row16 - iu * 3;
            const int uslot = (nn == 0) ? 13 : 9 + nn;   // um0->13, um1->10, um2->11
            #pragma unroll
            for (int t = 0; t < 4; ++t) {
                const int o = kg * 4 + t;
                bm_t[(o * 8 + o) * BMT_STRIDE + iu * 16 + uslot] = acc[t];
            }
        }
    }
    __syncthreads();   // bm_t readable

    // ---- Phase 2: pair tables.  thread = (i=w, x=lane>>3, y=lane&7) ----
    {
        const int i = w;
        const int x = lane >> 3;
        const int y = lane & 7;
        const float4 vxy = *(const float4*)&bm_t[(x * 8 + y) * BMT_STRIDE + i * 16 + 0];
        const float4 vyx = *(const float4*)&bm_t[(y * 8 + x) * BMT_STRIDE + i * 16 + 4];
        const float4 vyy = *(const float4*)&bm_t[(y * 8 + y) * BMT_STRIDE + i * 16 + 8];
        const float2 vxx = *(const float2*)&bm_t[(x * 8 + x) * BMT_STRIDE + i * 16 + 12];
        // vxy = [r1,r2,r5,-]  vyx = [r3,r6,r7,-]  vyy = [r4,r8,um1,um2]  vxx = [r0,um0]
        const float q01 = vxx.y + vyy.z + vxx.x + vyy.x + vxy.x + vyx.x;
        const float q02 = vyy.w + vyy.y + vxy.y + vyx.y;
        const float q12 = vxy.z + vyx.z;
        const int ro = (x * 4 + i) * QROW + y;
        q01_s[ro] = q01; q02_s[ro] = q02; q12_s[ro] = q12;
    }
    __syncthreads();   // q tables readable

    // ---- Phase 3: sweep. thread = (i=tid&3, ordered pair pr=tid>>2 <56) ----
    float mn = INFINITY;
    {
        const int i  = tid & 3;
        const int pr = tid >> 2;
        if (pr < 56) {
            const int a  = pr / 7;
            const int o  = pr - a * 7;
            const int bb = o + (o >= a);
            const float base = q01_s[(a * 4 + i) * QROW + bb];
            const float4 r2a = *(const float4*)&q02_s[(a  * 4 + i) * QROW];
            const float4 r2b = *(const float4*)&q02_s[(a  * 4 + i) * QROW + 4];
            const float4 r1a = *(const float4*)&q12_s[(bb * 4 + i) * QROW];
            const float4 r1b = *(const float4*)&q12_s[(bb * 4 + i) * QROW + 4];
            float v[8];
            v[0] = r2a.x + r1a.x; v[1] = r2a.y + r1a.y;
            v[2] = r2a.z + r1a.z; v[3] = r2a.w + r1a.w;
            v[4] = r2b.x + r1b.x; v[5] = r2b.y + r1b.y;
            v[6] = r2b.z + r1b.z; v[7] = r2b.w + r1b.w;
            #pragma unroll
            for (int cc = 0; cc < 8; ++cc) {
                const float s = (cc == a || cc == bb) ? INFINITY : (base + v[cc]);
                mn = fminf(mn, s);
            }
        }
    }

    mn = fminf(mn, __shfl_xor(mn, 4));
    mn = fminf(mn, __shfl_xor(mn, 8));
    mn = fminf(mn, __shfl_xor(mn, 16));
    mn = fminf(mn, __shfl_xor(mn, 32));

    if (lane < 4) wmin[w * 4 + lane] = mn;
    __syncthreads();

    if (tid == 0) {
        float m0 = fminf(fminf(wmin[0], wmin[4]), fminf(wmin[8],  wmin[12]));
        float m1 = fminf(fminf(wmin[1], wmin[5]), fminf(wmin[9],  wmin[13]));
        float m2 = fminf(fminf(wmin[2], wmin[6]), fminf(wmin[10], wmin[14]));
        float m3 = fminf(fminf(wmin[3], wmin[7]), fminf(wmin[11], wmin[15]));
        float mx = fmaxf(fmaxf(m0, m1), fmaxf(m2, m3));
        float e0 = expf(m0 - mx), e1 = expf(m1 - mx);
        float e2 = expf(m2 - mx), e3 = expf(m3 - mx);
        float inv = 1.f / (e0 + e1 + e2 + e3);
        *(float4*)(out + (size_t)b * 4) =
            make_float4((e0 + e1) * inv, (e2 + e3) * inv, 0.f, 0.f);
    }
}

extern "C" void kernel_launch(void* const* d_in, const int* in_sizes, int n_in,
                              void* d_out, int out_size, void* d_ws, size_t ws_size,
                              hipStream_t stream) {
    const float* uf = (const float*)d_in[0];   // (4096,8,64)
    const float* bf = (const float*)d_in[1];   // (4096,8,8,64)
    const float* ru = (const float*)d_in[2];   // (4,3,64)
    const float* rb = (const float*)d_in[3];   // (4,3,3,64)
    float* out = (float*)d_out;                // (4096,4)

    const int B = in_sizes[0] / (8 * 64);      // 4096

    rule_prep_kernel<<<1, 256, 0, stream>>>(ru, rb, (__bf16*)d_ws);
    rule_learner_kernel<<<B, 256, 0, stream>>>(uf, bf, (const bf16x8*)d_ws, out);
}